// Round 5
// baseline (475.552 us; speedup 1.0000x reference)
//
#include <hip/hip_runtime.h>
#include <hip/hip_bf16.h>
#include <stdint.h>

#define IMG_H 96
#define IMG_W 96
#define IMG_C 3
#define HO    90                 // 96-7+1
#define NPAT  8100               // 90*90
#define NPAD  8192
#define DDIM  147                // 3*7*7
#define KPAD  160                // padded K (5 chunks of 32)
#define NCHK  5
#define BATCH 4
#define TILE  128
#define ALPHA 0.05f

typedef __attribute__((ext_vector_type(8))) short short8;
typedef __attribute__((ext_vector_type(4))) float f32x4;

// ---------- patch extraction + squared norms (+ min-init, + out zero) ----------
__global__ __launch_bounds__(256) void extract_patches(
    const float* __restrict__ img,          // [B][3][96][96]
    __hip_bfloat16* __restrict__ pat,       // [B][NPAD][KPAD]
    float* __restrict__ nrm,                // [B][NPAD]
    unsigned* __restrict__ mininit,         // row_min or col_min -> +inf
    float* __restrict__ outzero)            // may be null
{
    int wid  = threadIdx.x >> 6;
    int lane = threadIdx.x & 63;
    int pidx = blockIdx.x * 4 + wid;        // 0..8191
    int b    = blockIdx.y;
    if (pidx >= NPAD) return;
    if (outzero && blockIdx.x == 0 && blockIdx.y == 0 && threadIdx.x == 0)
        outzero[0] = 0.f;
    const float* im = img + (size_t)b * (IMG_C * IMG_H * IMG_W);
    __hip_bfloat16* pp = pat + ((size_t)b * NPAD + pidx) * KPAD;
    int r = pidx / HO, c = pidx - r * HO;
    bool valid = pidx < NPAT;
    float ss = 0.f;
    for (int d = lane; d < KPAD; d += 64) {
        float v = 0.f;
        if (valid && d < DDIM) {
            int ch  = d / 49;
            int rem = d - ch * 49;
            int pr  = rem / 7, pc = rem - pr * 7;
            v = im[ch * (IMG_H * IMG_W) + (r + pr) * IMG_W + (c + pc)];
        }
        pp[d] = __float2bfloat16(v);
        ss += v * v;
    }
    for (int s = 32; s; s >>= 1) ss += __shfl_down(ss, s);
    if (lane == 0) {
        nrm[(size_t)b * NPAD + pidx] = ss;
        mininit[(size_t)b * NPAD + pidx] = 0x7f800000u;  // +inf bits
    }
}

// -------------------- fused GEMM + min epilogues --------------------
// Barrier-free main loop: MFMA fragments loaded DIRECTLY from global
// (L2-resident panels; 16B/lane fully-coalesced 64B segments). No LDS tiles,
// no global_load_lds, no vmcnt(0) drains — compiler pipelines loads freely.
template <int PASS>
__global__ __launch_bounds__(256, 4) void gemm_pass(
    const __hip_bfloat16* __restrict__ Xp,   // [B][NPAD][KPAD] cols i
    const __hip_bfloat16* __restrict__ Yp,   // [B][NPAD][KPAD] rows j
    const float* __restrict__ x2,
    const float* __restrict__ y2,
    unsigned* __restrict__ row_min,
    unsigned* __restrict__ col_min)
{
    __shared__ float y2s[TILE], x2s[TILE], rms[TILE];

    int bz  = blockIdx.z;
    int tI  = blockIdx.x;   // col tile (fast) -> B panels cycle within XCD L2
    int tJ  = blockIdx.y;   // row tile (slow) -> A panel reused
    int tid = threadIdx.x;
    int wid = tid >> 6, lane = tid & 63;
    int wr = wid >> 1, wc = wid & 1;

    const __hip_bfloat16* Abase = Yp + ((size_t)bz * NPAD + tJ * TILE) * KPAD;
    const __hip_bfloat16* Bbase = Xp + ((size_t)bz * NPAD + tI * TILE) * KPAD;

    // epilogue scalars -> LDS broadcast
    if (tid < TILE) {
        y2s[tid] = y2[(size_t)bz * NPAD + tJ * TILE + tid];
        if (PASS == 2) {
            float rm = __uint_as_float(row_min[(size_t)bz * NPAD + tJ * TILE + tid]);
            rms[tid] = 1.0f / (rm + ALPHA);  // +inf pad row -> 0, masked later
        }
    } else {
        int t = tid - TILE;
        x2s[t] = x2[(size_t)bz * NPAD + tI * TILE + t];
    }
    __syncthreads();

    // per-lane fragment base pointers (row-major [row][KPAD], 16B aligned)
    int arow = wr * 64 + (lane & 15);
    int brow = wc * 64 + (lane & 15);
    int koff = (lane >> 4) * 8;
    const __hip_bfloat16* Ap = Abase + (size_t)arow * KPAD + koff;
    const __hip_bfloat16* Bp = Bbase + (size_t)brow * KPAD + koff;

    f32x4 acc[4][4] = {};
    for (int c = 0; c < NCHK; ++c) {
        short8 a[4], b[4];
        for (int m = 0; m < 4; ++m)
            a[m] = *(const short8*)(Ap + m * (16 * KPAD) + c * 32);
        for (int n = 0; n < 4; ++n)
            b[n] = *(const short8*)(Bp + n * (16 * KPAD) + c * 32);
        for (int m = 0; m < 4; ++m)
            for (int n = 0; n < 4; ++n)
                acc[m][n] = __builtin_amdgcn_mfma_f32_16x16x32_bf16(
                    a[m], b[n], acc[m][n], 0, 0, 0);
    }

    // ---- epilogue ----
    const float invD = 1.0f / (float)DDIM;
    int rbase_l = wr * 64 + (lane >> 4) * 4;  // + m*16 + reg
    int cbase_l = wc * 64 + (lane & 15);      // + n*16
    int growb = tJ * TILE;
    int gcolb = tI * TILE;

    float xv[4];
    for (int n = 0; n < 4; ++n) xv[n] = x2s[cbase_l + n * 16];

    if (PASS == 1) {
        for (int m = 0; m < 4; ++m)
            for (int reg = 0; reg < 4; ++reg) {
                int lr = rbase_l + m * 16 + reg;
                float yv = y2s[lr];
                float rmin = __builtin_inff();
                for (int n = 0; n < 4; ++n) {
                    float dd = (yv + xv[n] - 2.0f * acc[m][n][reg]) * invD;
                    dd = fmaxf(dd, 0.0f);
                    if (gcolb + cbase_l + n * 16 >= NPAT) dd = __builtin_inff();
                    rmin = fminf(rmin, dd);
                }
                for (int s = 1; s < 16; s <<= 1)
                    rmin = fminf(rmin, __shfl_xor(rmin, s));
                int grow = growb + lr;
                if ((lane & 15) == 0 && grow < NPAT)
                    atomicMin(&row_min[(size_t)bz * NPAD + grow],
                              __float_as_uint(rmin));
            }
    } else {
        for (int n = 0; n < 4; ++n) {
            float cmin = __builtin_inff();
            for (int m = 0; m < 4; ++m)
                for (int reg = 0; reg < 4; ++reg) {
                    int lr = rbase_l + m * 16 + reg;
                    float dd = (y2s[lr] + xv[n] - 2.0f * acc[m][n][reg]) * invD;
                    dd = fmaxf(dd, 0.0f);
                    float v = dd * rms[lr];
                    if (growb + lr >= NPAT) v = __builtin_inff();
                    cmin = fminf(cmin, v);
                }
            cmin = fminf(cmin, __shfl_xor(cmin, 16));
            cmin = fminf(cmin, __shfl_xor(cmin, 32));
            int gcol = gcolb + cbase_l + n * 16;
            if ((lane >> 4) == 0 && gcol < NPAT)
                atomicMin(&col_min[(size_t)bz * NPAD + gcol],
                          __float_as_uint(cmin));
        }
    }
}

// -------------------- final mean (parallel, scaled atomicAdd) --------------------
__global__ __launch_bounds__(256) void final_reduce(
    const unsigned* __restrict__ col_min, float* __restrict__ out)
{
    __shared__ float sdata[256];
    float s = 0.f;
    for (int idx = blockIdx.x * 256 + threadIdx.x; idx < BATCH * NPAT;
         idx += gridDim.x * 256) {
        int b = idx / NPAT;
        int i = idx - b * NPAT;
        s += __uint_as_float(col_min[(size_t)b * NPAD + i]);
    }
    sdata[threadIdx.x] = s;
    __syncthreads();
    for (int t = 128; t; t >>= 1) {
        if (threadIdx.x < t) sdata[threadIdx.x] += sdata[threadIdx.x + t];
        __syncthreads();
    }
    if (threadIdx.x == 0)
        atomicAdd(out, sdata[0] * (1.0f / (float)(BATCH * NPAT)));
}

extern "C" void kernel_launch(void* const* d_in, const int* in_sizes, int n_in,
                              void* d_out, int out_size, void* d_ws, size_t ws_size,
                              hipStream_t stream) {
    const float* x = (const float*)d_in[0];
    const float* y = (const float*)d_in[1];
    float* out = (float*)d_out;

    char* ws = (char*)d_ws;
    size_t patSz = (size_t)BATCH * NPAD * KPAD * sizeof(__hip_bfloat16); // 10.5 MB
    __hip_bfloat16* Xp = (__hip_bfloat16*)ws;
    __hip_bfloat16* Yp = (__hip_bfloat16*)(ws + patSz);
    float* x2 = (float*)(ws + 2 * patSz);
    float* y2 = x2 + BATCH * NPAD;
    unsigned* row_min = (unsigned*)(y2 + BATCH * NPAD);
    unsigned* col_min = row_min + BATCH * NPAD;

    dim3 eg(NPAD / 4, BATCH);
    // x-extract inits col_min and zeroes out; y-extract inits row_min
    extract_patches<<<eg, 256, 0, stream>>>(x, Xp, x2, col_min, out);
    extract_patches<<<eg, 256, 0, stream>>>(y, Yp, y2, row_min, nullptr);

    dim3 gg(NPAD / TILE, NPAD / TILE, BATCH);   // (64, 64, 4)
    gemm_pass<1><<<gg, 256, 0, stream>>>(Xp, Yp, x2, y2, row_min, col_min);
    gemm_pass<2><<<gg, 256, 0, stream>>>(Xp, Yp, x2, y2, row_min, col_min);

    final_reduce<<<64, 256, 0, stream>>>(col_min, out);
}

// Round 6
// 426.858 us; speedup vs baseline: 1.1141x; 1.1141x over previous
//
#include <hip/hip_runtime.h>
#include <hip/hip_bf16.h>
#include <stdint.h>

#define IMG_H 96
#define IMG_W 96
#define IMG_C 3
#define HO    90                 // 96-7+1
#define NPAT  8100               // 90*90
#define NPAD  8192
#define DDIM  147                // 3*7*7
#define KPAD  160                // padded K (5 chunks of 32)
#define NCHK  5
#define BATCH 4
#define TILE  128
#define ALPHA 0.05f

typedef __attribute__((ext_vector_type(8))) short short8;
typedef __attribute__((ext_vector_type(4))) float f32x4;

__device__ __forceinline__ void async16(const void* g, void* l) {
    __builtin_amdgcn_global_load_lds(
        (const __attribute__((address_space(1))) unsigned int*)g,
        (__attribute__((address_space(3))) unsigned int*)l,
        16, 0, 0);
}

// ---------- patch extraction + squared norms (+ min-init, + out zero) ----------
__global__ __launch_bounds__(256) void extract_patches(
    const float* __restrict__ img,          // [B][3][96][96]
    __hip_bfloat16* __restrict__ pat,       // [B][NPAD][KPAD]
    float* __restrict__ nrm,                // [B][NPAD]
    unsigned* __restrict__ mininit,         // row_min or col_min -> +inf
    float* __restrict__ outzero)            // may be null
{
    int wid  = threadIdx.x >> 6;
    int lane = threadIdx.x & 63;
    int pidx = blockIdx.x * 4 + wid;        // 0..8191
    int b    = blockIdx.y;
    if (pidx >= NPAD) return;
    if (outzero && blockIdx.x == 0 && blockIdx.y == 0 && threadIdx.x == 0)
        outzero[0] = 0.f;
    const float* im = img + (size_t)b * (IMG_C * IMG_H * IMG_W);
    __hip_bfloat16* pp = pat + ((size_t)b * NPAD + pidx) * KPAD;
    int r = pidx / HO, c = pidx - r * HO;
    bool valid = pidx < NPAT;
    float ss = 0.f;
    for (int d = lane; d < KPAD; d += 64) {
        float v = 0.f;
        if (valid && d < DDIM) {
            int ch  = d / 49;
            int rem = d - ch * 49;
            int pr  = rem / 7, pc = rem - pr * 7;
            v = im[ch * (IMG_H * IMG_W) + (r + pr) * IMG_W + (c + pc)];
        }
        pp[d] = __float2bfloat16(v);
        ss += v * v;
    }
    for (int s = 32; s; s >>= 1) ss += __shfl_down(ss, s);
    if (lane == 0) {
        nrm[(size_t)b * NPAD + pidx] = ss;
        mininit[(size_t)b * NPAD + pidx] = 0x7f800000u;  // +inf bits
    }
}

// -------------------- fused GEMM + min epilogues --------------------
// R4 base + T3/T4: triple-buffered chunks, depth-2 prefetch, counted vmcnt
// (loads stay in flight ACROSS barriers), ONE raw s_barrier per chunk.
// LDS XOR-swizzle kept (0 conflicts). T5 setprio around MFMA cluster.
template <int PASS>
__global__ __launch_bounds__(256, 3) void gemm_pass(
    const __hip_bfloat16* __restrict__ Xp,   // [B][NPAD][KPAD] cols i
    const __hip_bfloat16* __restrict__ Yp,   // [B][NPAD][KPAD] rows j
    const float* __restrict__ x2,
    const float* __restrict__ y2,
    unsigned* __restrict__ row_min,
    unsigned* __restrict__ col_min)
{
    __shared__ __align__(16) __hip_bfloat16 Alds[3][TILE * 32];  // 3 x 8 KB
    __shared__ __align__(16) __hip_bfloat16 Blds[3][TILE * 32];  // 3 x 8 KB
    __shared__ float y2s[TILE], x2s[TILE], rms[TILE];

    int bz  = blockIdx.z;
    int tI  = blockIdx.x;   // col tile
    int tJ  = blockIdx.y;   // row tile
    int tid = threadIdx.x;
    int wid = tid >> 6, lane = tid & 63;
    int wr = wid >> 1, wc = wid & 1;

    const __hip_bfloat16* Abase = Yp + ((size_t)bz * NPAD + tJ * TILE) * KPAD;
    const __hip_bfloat16* Bbase = Xp + ((size_t)bz * NPAD + tI * TILE) * KPAD;

    // epilogue scalars -> LDS (covered by first in-loop barrier + lgkmcnt)
    if (tid < TILE) {
        y2s[tid] = y2[(size_t)bz * NPAD + tJ * TILE + tid];
        if (PASS == 2) {
            float rm = __uint_as_float(row_min[(size_t)bz * NPAD + tJ * TILE + tid]);
            rms[tid] = 1.0f / (rm + ALPHA);  // +inf pad row -> 0, masked later
        }
    } else {
        int t = tid - TILE;
        x2s[t] = x2[(size_t)bz * NPAD + tI * TILE + t];
    }

    int srow = (lane >> 2);          // row within 16-row subtile
    int sst  = (lane & 3);           // linear stored 16B slot

    // stage chunk c of A and B into buffer `buf` (4 async16 / thread)
    auto stage = [&](int buf, int c) {
        for (int qq = 0; qq < 2; ++qq) {
            int q    = wid * 2 + qq;
            int row  = q * 16 + srow;
            int slog = sst ^ ((row >> 1) & 3);            // inverse swz on src
            size_t goff = (size_t)row * KPAD + c * 32 + slog * 8;
            async16(Abase + goff, &Alds[buf][q * 512]);
            async16(Bbase + goff, &Blds[buf][q * 512]);
        }
    };

    // prologue: chunks 0,1 in flight (8 VMEM ops / thread outstanding)
    stage(0, 0);
    stage(1, 1);

    f32x4 acc[4][4] = {};
    int arow  = wr * 64 + (lane & 15);
    int brow  = wc * 64 + (lane & 15);
    int sread = ((lane >> 4) ^ ((lane >> 1) & 3)) * 8;    // swz read slot

#pragma unroll
    for (int c = 0; c < NCHK; ++c) {
        // counted wait: chunk c landed, chunk c+1 (4 ops) may stay in flight
        if (c < NCHK - 1)
            asm volatile("s_waitcnt vmcnt(4) lgkmcnt(0)" ::: "memory");
        else
            asm volatile("s_waitcnt vmcnt(0) lgkmcnt(0)" ::: "memory");
        __builtin_amdgcn_s_barrier();
        asm volatile("" ::: "memory");   // fence: keep LDS reads below barrier

        // depth-2 prefetch: safe to overwrite buf (c+2)%3 == (c-1)%3 now —
        // barrier above guarantees all waves finished iteration c-1 reads.
        if (c + 2 < NCHK) stage((c + 2) % 3, c + 2);

        const int cur = c % 3;
        short8 a[4], b[4];
        for (int m = 0; m < 4; ++m)
            a[m] = *(const short8*)&Alds[cur][(arow + m * 16) * 32 + sread];
        for (int n = 0; n < 4; ++n)
            b[n] = *(const short8*)&Blds[cur][(brow + n * 16) * 32 + sread];
        __builtin_amdgcn_s_setprio(1);
        for (int m = 0; m < 4; ++m)
            for (int n = 0; n < 4; ++n)
                acc[m][n] = __builtin_amdgcn_mfma_f32_16x16x32_bf16(
                    a[m], b[n], acc[m][n], 0, 0, 0);
        __builtin_amdgcn_s_setprio(0);
    }

    // ---- epilogue ----
    const float invD = 1.0f / (float)DDIM;
    int rbase_l = wr * 64 + (lane >> 4) * 4;  // + m*16 + reg
    int cbase_l = wc * 64 + (lane & 15);      // + n*16
    int growb = tJ * TILE;
    int gcolb = tI * TILE;

    float xv[4];
    for (int n = 0; n < 4; ++n) xv[n] = x2s[cbase_l + n * 16];

    if (PASS == 1) {
        for (int m = 0; m < 4; ++m)
            for (int reg = 0; reg < 4; ++reg) {
                int lr = rbase_l + m * 16 + reg;
                float yv = y2s[lr];
                float rmin = __builtin_inff();
                for (int n = 0; n < 4; ++n) {
                    float dd = (yv + xv[n] - 2.0f * acc[m][n][reg]) * invD;
                    dd = fmaxf(dd, 0.0f);
                    if (gcolb + cbase_l + n * 16 >= NPAT) dd = __builtin_inff();
                    rmin = fminf(rmin, dd);
                }
                for (int s = 1; s < 16; s <<= 1)
                    rmin = fminf(rmin, __shfl_xor(rmin, s));
                int grow = growb + lr;
                if ((lane & 15) == 0 && grow < NPAT)
                    atomicMin(&row_min[(size_t)bz * NPAD + grow],
                              __float_as_uint(rmin));
            }
    } else {
        for (int n = 0; n < 4; ++n) {
            float cmin = __builtin_inff();
            for (int m = 0; m < 4; ++m)
                for (int reg = 0; reg < 4; ++reg) {
                    int lr = rbase_l + m * 16 + reg;
                    float dd = (y2s[lr] + xv[n] - 2.0f * acc[m][n][reg]) * invD;
                    dd = fmaxf(dd, 0.0f);
                    float v = dd * rms[lr];
                    if (growb + lr >= NPAT) v = __builtin_inff();
                    cmin = fminf(cmin, v);
                }
            cmin = fminf(cmin, __shfl_xor(cmin, 16));
            cmin = fminf(cmin, __shfl_xor(cmin, 32));
            int gcol = gcolb + cbase_l + n * 16;
            if ((lane >> 4) == 0 && gcol < NPAT)
                atomicMin(&col_min[(size_t)bz * NPAD + gcol],
                          __float_as_uint(cmin));
        }
    }
}

// -------------------- final mean (parallel, scaled atomicAdd) --------------------
__global__ __launch_bounds__(256) void final_reduce(
    const unsigned* __restrict__ col_min, float* __restrict__ out)
{
    __shared__ float sdata[256];
    float s = 0.f;
    for (int idx = blockIdx.x * 256 + threadIdx.x; idx < BATCH * NPAT;
         idx += gridDim.x * 256) {
        int b = idx / NPAT;
        int i = idx - b * NPAT;
        s += __uint_as_float(col_min[(size_t)b * NPAD + i]);
    }
    sdata[threadIdx.x] = s;
    __syncthreads();
    for (int t = 128; t; t >>= 1) {
        if (threadIdx.x < t) sdata[threadIdx.x] += sdata[threadIdx.x + t];
        __syncthreads();
    }
    if (threadIdx.x == 0)
        atomicAdd(out, sdata[0] * (1.0f / (float)(BATCH * NPAT)));
}

extern "C" void kernel_launch(void* const* d_in, const int* in_sizes, int n_in,
                              void* d_out, int out_size, void* d_ws, size_t ws_size,
                              hipStream_t stream) {
    const float* x = (const float*)d_in[0];
    const float* y = (const float*)d_in[1];
    float* out = (float*)d_out;

    char* ws = (char*)d_ws;
    size_t patSz = (size_t)BATCH * NPAD * KPAD * sizeof(__hip_bfloat16); // 10.5 MB
    __hip_bfloat16* Xp = (__hip_bfloat16*)ws;
    __hip_bfloat16* Yp = (__hip_bfloat16*)(ws + patSz);
    float* x2 = (float*)(ws + 2 * patSz);
    float* y2 = x2 + BATCH * NPAD;
    unsigned* row_min = (unsigned*)(y2 + BATCH * NPAD);
    unsigned* col_min = row_min + BATCH * NPAD;

    dim3 eg(NPAD / 4, BATCH);
    // x-extract inits col_min and zeroes out; y-extract inits row_min
    extract_patches<<<eg, 256, 0, stream>>>(x, Xp, x2, col_min, out);
    extract_patches<<<eg, 256, 0, stream>>>(y, Yp, y2, row_min, nullptr);

    dim3 gg(NPAD / TILE, NPAD / TILE, BATCH);   // (64, 64, 4)
    gemm_pass<1><<<gg, 256, 0, stream>>>(Xp, Yp, x2, y2, row_min, col_min);
    gemm_pass<2><<<gg, 256, 0, stream>>>(Xp, Yp, x2, y2, row_min, col_min);

    final_reduce<<<64, 256, 0, stream>>>(col_min, out);
}

// Round 7
// 280.827 us; speedup vs baseline: 1.6934x; 1.5200x over previous
//
#include <hip/hip_runtime.h>
#include <hip/hip_bf16.h>
#include <stdint.h>

#define IMG_H 96
#define IMG_W 96
#define IMG_C 3
#define HO    90                 // 96-7+1
#define NPAT  8100               // 90*90
#define NPAD  8192
#define DDIM  147                // 3*7*7
#define KPAD  160                // padded K (5 chunks of 32)
#define NCHK  5
#define BATCH 4
#define TILE  128
#define NT    (NPAD / TILE)      // 64 stream tiles
#define ALPHA 0.05f

typedef __attribute__((ext_vector_type(8))) short short8;
typedef __attribute__((ext_vector_type(4))) float f32x4;

__device__ __forceinline__ void async16(const void* g, void* l) {
    __builtin_amdgcn_global_load_lds(
        (const __attribute__((address_space(1))) unsigned int*)g,
        (__attribute__((address_space(3))) unsigned int*)l,
        16, 0, 0);
}

// ---------- patch extraction + squared norms (+ out zero) ----------
__global__ __launch_bounds__(256) void extract_patches(
    const float* __restrict__ img,          // [B][3][96][96]
    __hip_bfloat16* __restrict__ pat,       // [B][NPAD][KPAD]
    float* __restrict__ nrm,                // [B][NPAD]
    float* __restrict__ outzero)            // may be null
{
    int wid  = threadIdx.x >> 6;
    int lane = threadIdx.x & 63;
    int pidx = blockIdx.x * 4 + wid;        // 0..8191
    int b    = blockIdx.y;
    if (pidx >= NPAD) return;
    if (outzero && blockIdx.x == 0 && blockIdx.y == 0 && threadIdx.x == 0)
        outzero[0] = 0.f;
    const float* im = img + (size_t)b * (IMG_C * IMG_H * IMG_W);
    __hip_bfloat16* pp = pat + ((size_t)b * NPAD + pidx) * KPAD;
    int r = pidx / HO, c = pidx - r * HO;
    bool valid = pidx < NPAT;
    float ss = 0.f;
    for (int d = lane; d < KPAD; d += 64) {
        float v = 0.f;
        if (valid && d < DDIM) {
            int ch  = d / 49;
            int rem = d - ch * 49;
            int pr  = rem / 7, pc = rem - pr * 7;
            v = im[ch * (IMG_H * IMG_W) + (r + pr) * IMG_W + (c + pc)];
        }
        pp[d] = __float2bfloat16(v);
        ss += v * v;
    }
    for (int s = 32; s; s >>= 1) ss += __shfl_down(ss, s);
    if (lane == 0) nrm[(size_t)b * NPAD + pidx] = ss;
}

// ---------- rms prep: fold invD + pad-row mask ----------
__global__ __launch_bounds__(256) void prep_rms(
    const float* __restrict__ row_min, float* __restrict__ rms)
{
    int i = blockIdx.x * 256 + threadIdx.x;
    if (i < BATCH * NPAD) {
        int j = i & (NPAD - 1);
        float rm = row_min[i];
        rms[i] = (j < NPAT) ? (1.0f / (float)DDIM) / (rm + ALPHA)
                            : __builtin_inff();
    }
}

// -------------------- panel-persistent fused GEMM passes --------------------
// PASS 1: block owns 128 rows (Y panel in LDS), streams all X tiles;
//         row-min kept in registers; ONE plain store per row. No atomics.
// PASS 2: block owns 128 cols (X panel), streams Y tiles + y2/rms smalls;
//         col-min in registers; one atomicAdd partial per block.
template <int PASS>
__global__ __launch_bounds__(256, 1) void panel_pass(
    const __hip_bfloat16* __restrict__ Xp,   // [B][NPAD][KPAD]
    const __hip_bfloat16* __restrict__ Yp,   // [B][NPAD][KPAD]
    const float* __restrict__ x2,
    const float* __restrict__ y2,
    const float* __restrict__ rms,           // PASS2 only
    float* __restrict__ row_min,
    float* __restrict__ out)                 // PASS2 only
{
    __shared__ __align__(16) __hip_bfloat16 Plds[NCHK * TILE * 32];     // 40 KB
    __shared__ __align__(16) __hip_bfloat16 Slds[2][NCHK * TILE * 32];  // 80 KB
    __shared__ float sm_a[2][TILE];   // stream smalls: x2 (P1) / y2 (P2)
    __shared__ float sm_b[2][TILE];   // P2: rms
    __shared__ float pnl[TILE];       // panel small: y2 (P1) / x2 (P2)
    __shared__ float red[2][TILE];    // final cross-wave reduce

    int blk = blockIdx.x;
    int bz  = blk & 3;               // image: constant per XCD (round-robin %8)
    int tP  = blk >> 2;              // panel index 0..63
    int tid = threadIdx.x;
    int wid = tid >> 6, lane = tid & 63;
    int wr = wid >> 1, wc = wid & 1;

    const __hip_bfloat16* Pbase =
        (PASS == 1 ? Yp : Xp) + ((size_t)bz * NPAD + tP * TILE) * KPAD;
    const __hip_bfloat16* Sbase =
        (PASS == 1 ? Xp : Yp) + (size_t)bz * NPAD * KPAD;
    const float* pnl_src = (PASS == 1 ? y2 : x2) + (size_t)bz * NPAD + tP * TILE;
    const float* sma_src = (PASS == 1 ? x2 : y2) + (size_t)bz * NPAD;
    const float* smb_src = rms + (size_t)bz * NPAD;

    int srow = lane >> 2;            // row within 16-row subtile
    int sst  = lane & 3;             // linear stored 16B slot

    auto stage_big = [&](__hip_bfloat16* dst, const __hip_bfloat16* gsrc) {
        for (int c = 0; c < NCHK; ++c)
            for (int qq = 0; qq < 2; ++qq) {
                int q    = wid * 2 + qq;
                int row  = q * 16 + srow;
                int slog = sst ^ ((row >> 1) & 3);      // inverse swz on src
                async16(gsrc + (size_t)row * KPAD + c * 32 + slog * 8,
                        dst + c * 4096 + q * 512);
            }
    };
    auto stage_small = [&](int buf, int t) {
        if (wid == 0 && lane < 32)
            async16(sma_src + t * TILE + lane * 4, &sm_a[buf][0]);
        if (PASS == 2 && wid == 1 && lane < 32)
            async16(smb_src + t * TILE + lane * 4, &sm_b[buf][0]);
    };

    // prologue: panel + first stream tile + smalls
    stage_big(Plds, Pbase);
    stage_big(&Slds[0][0], Sbase);
    stage_small(0, 0);
    if (wid == 2 && lane < 32) async16(pnl_src + lane * 4, &pnl[0]);
    __syncthreads();   // drains all prologue loads (compiler vmcnt(0))

    int arow  = wr * 64 + (lane & 15);
    int brow  = wc * 64 + (lane & 15);
    int sread = ((lane >> 4) ^ ((lane >> 1) & 3)) * 8;  // swz read slot
    int rbase_l = wr * 64 + (lane >> 4) * 4;
    int cbase_l = wc * 64 + (lane & 15);

    float xv[4];   // PASS2: own cols' x2 (fixed)
    if (PASS == 2)
        for (int n = 0; n < 4; ++n) xv[n] = pnl[cbase_l + n * 16];

    float runmin[16];
    for (int i = 0; i < 16; ++i) runmin[i] = __builtin_inff();

#pragma unroll 1
    for (int t = 0; t < NT; ++t) {
        int cur = t & 1;
        // prefetch next tile into other buffer (overlaps compute below;
        // buffer reuse safe: barrier at end of t-1 covered all its readers)
        if (t + 1 < NT) {
            stage_big(&Slds[cur ^ 1][0], Sbase + (size_t)(t + 1) * TILE * KPAD);
            stage_small(cur ^ 1, t + 1);
        }

        const __hip_bfloat16* Al = (PASS == 1) ? Plds : &Slds[cur][0];
        const __hip_bfloat16* Bl = (PASS == 1) ? &Slds[cur][0] : Plds;

        f32x4 acc[4][4] = {};
        for (int c = 0; c < NCHK; ++c) {
            short8 a[4], b[4];
            for (int m = 0; m < 4; ++m)
                a[m] = *(const short8*)&Al[c * 4096 + (arow + m * 16) * 32 + sread];
            for (int n = 0; n < 4; ++n)
                b[n] = *(const short8*)&Bl[c * 4096 + (brow + n * 16) * 32 + sread];
            for (int m = 0; m < 4; ++m)
                for (int n = 0; n < 4; ++n)
                    acc[m][n] = __builtin_amdgcn_mfma_f32_16x16x32_bf16(
                        a[m], b[n], acc[m][n], 0, 0, 0);
        }

        if (PASS == 1) {
            // row-min of raw (x2 - 2*cross); y2/invD/clamp folded in at end
            float xvn[4];
            int gcb = t * TILE;
            for (int n = 0; n < 4; ++n) {
                float xx = sm_a[cur][cbase_l + n * 16];
                xvn[n] = (gcb + cbase_l + n * 16 < NPAT) ? xx : __builtin_inff();
            }
            for (int m = 0; m < 4; ++m)
                for (int reg = 0; reg < 4; ++reg)
                    for (int n = 0; n < 4; ++n)
                        runmin[m * 4 + reg] = fminf(runmin[m * 4 + reg],
                            fmaf(-2.0f, acc[m][n][reg], xvn[n]));
        } else {
            // col-min of (y2 + x2 - 2c) * rms'; rms' = invD/(rm+a), +inf pads;
            // clamp deferred to final (max(.,0) monotone => exact)
            for (int m = 0; m < 4; ++m)
                for (int reg = 0; reg < 4; ++reg) {
                    int lr = rbase_l + m * 16 + reg;
                    float yv = sm_a[cur][lr];
                    float rr = sm_b[cur][lr];
                    for (int n = 0; n < 4; ++n)
                        runmin[n] = fminf(runmin[n],
                            fmaf(-2.0f, acc[m][n][reg], yv + xv[n]) * rr);
                }
        }
        __syncthreads();   // drains prefetch vmcnt + handshakes buffers
    }

    if (PASS == 1) {
        // 16-lane col-group reduce -> cross-wc LDS reduce -> plain store
        for (int m = 0; m < 4; ++m)
            for (int reg = 0; reg < 4; ++reg) {
                float v = runmin[m * 4 + reg];
                for (int s = 1; s < 16; s <<= 1)
                    v = fminf(v, __shfl_xor(v, s));
                if ((lane & 15) == 0)
                    red[wc][rbase_l + m * 16 + reg] = v;
            }
        __syncthreads();
        if (tid < TILE) {
            float mv = fminf(red[0][tid], red[1][tid]);
            float rm = fmaxf(pnl[tid] + mv, 0.f) * (1.0f / (float)DDIM);
            row_min[(size_t)bz * NPAD + tP * TILE + tid] = rm;
        }
    } else {
        // cross row-group reduce -> cross-wr LDS reduce -> block sum -> 1 atomic
        for (int n = 0; n < 4; ++n) {
            float v = runmin[n];
            v = fminf(v, __shfl_xor(v, 16));
            v = fminf(v, __shfl_xor(v, 32));
            if (lane < 16) red[wr][wc * 64 + n * 16 + lane] = v;
        }
        __syncthreads();
        if (tid < TILE) {
            int gc = tP * TILE + tid;
            float cv = fminf(red[0][tid], red[1][tid]);
            cv = fmaxf(cv, 0.f);                       // deferred clamp
            red[0][tid] = (gc < NPAT) ? cv : 0.f;      // mask pad cols (+NaN)
        }
        __syncthreads();
        if (tid < 64) {
            float s = red[0][tid] + red[0][tid + 64];
            for (int o = 32; o; o >>= 1) s += __shfl_down(s, o);
            if (tid == 0)
                atomicAdd(out, s * (1.0f / (float)(BATCH * NPAT)));
        }
    }
}

extern "C" void kernel_launch(void* const* d_in, const int* in_sizes, int n_in,
                              void* d_out, int out_size, void* d_ws, size_t ws_size,
                              hipStream_t stream) {
    const float* x = (const float*)d_in[0];
    const float* y = (const float*)d_in[1];
    float* out = (float*)d_out;

    char* ws = (char*)d_ws;
    size_t patSz = (size_t)BATCH * NPAD * KPAD * sizeof(__hip_bfloat16); // 10.5 MB
    __hip_bfloat16* Xp = (__hip_bfloat16*)ws;
    __hip_bfloat16* Yp = (__hip_bfloat16*)(ws + patSz);
    float* x2 = (float*)(ws + 2 * patSz);
    float* y2 = x2 + BATCH * NPAD;
    float* row_min = y2 + BATCH * NPAD;
    float* rms = row_min + BATCH * NPAD;

    dim3 eg(NPAD / 4, BATCH);
    extract_patches<<<eg, 256, 0, stream>>>(x, Xp, x2, out);   // zeroes out
    extract_patches<<<eg, 256, 0, stream>>>(y, Yp, y2, nullptr);

    panel_pass<1><<<NT * BATCH, 256, 0, stream>>>(Xp, Yp, x2, y2, rms,
                                                  row_min, out);
    prep_rms<<<(BATCH * NPAD) / 256, 256, 0, stream>>>(row_min, rms);
    panel_pass<2><<<NT * BATCH, 256, 0, stream>>>(Xp, Yp, x2, y2, rms,
                                                  row_min, out);
}

// Round 8
// 225.872 us; speedup vs baseline: 2.1054x; 1.2433x over previous
//
#include <hip/hip_runtime.h>
#include <hip/hip_bf16.h>
#include <stdint.h>

#define IMG_H 96
#define IMG_W 96
#define IMG_C 3
#define HO    90                 // 96-7+1
#define NPAT  8100               // 90*90
#define NPAD  8192
#define DDIM  147                // 3*7*7
#define KPAD  160                // padded K (5 chunks of 32)
#define NCHK  5
#define BATCH 4
#define TILE  128
#define NT    (NPAD / TILE)      // 64 stream tiles
#define ALPHA 0.05f

typedef __attribute__((ext_vector_type(8))) short short8;
typedef __attribute__((ext_vector_type(4))) float f32x4;

__device__ __forceinline__ void async16(const void* g, void* l) {
    __builtin_amdgcn_global_load_lds(
        (const __attribute__((address_space(1))) unsigned int*)g,
        (__attribute__((address_space(3))) unsigned int*)l,
        16, 0, 0);
}

// ---------- patch extraction + squared norms (+ out zero) ----------
__global__ __launch_bounds__(256) void extract_patches(
    const float* __restrict__ img,          // [B][3][96][96]
    __hip_bfloat16* __restrict__ pat,       // [B][NPAD][KPAD]
    float* __restrict__ nrm,                // [B][NPAD]
    float* __restrict__ outzero)            // may be null
{
    int wid  = threadIdx.x >> 6;
    int lane = threadIdx.x & 63;
    int pidx = blockIdx.x * 4 + wid;        // 0..8191
    int b    = blockIdx.y;
    if (pidx >= NPAD) return;
    if (outzero && blockIdx.x == 0 && blockIdx.y == 0 && threadIdx.x == 0)
        outzero[0] = 0.f;
    const float* im = img + (size_t)b * (IMG_C * IMG_H * IMG_W);
    __hip_bfloat16* pp = pat + ((size_t)b * NPAD + pidx) * KPAD;
    int r = pidx / HO, c = pidx - r * HO;
    bool valid = pidx < NPAT;
    float ss = 0.f;
    for (int d = lane; d < KPAD; d += 64) {
        float v = 0.f;
        if (valid && d < DDIM) {
            int ch  = d / 49;
            int rem = d - ch * 49;
            int pr  = rem / 7, pc = rem - pr * 7;
            v = im[ch * (IMG_H * IMG_W) + (r + pr) * IMG_W + (c + pc)];
        }
        pp[d] = __float2bfloat16(v);
        ss += v * v;
    }
    for (int s = 32; s; s >>= 1) ss += __shfl_down(ss, s);
    if (lane == 0) nrm[(size_t)b * NPAD + pidx] = ss;
}

// ---------- rms prep: fold invD + pad-row mask ----------
__global__ __launch_bounds__(256) void prep_rms(
    const float* __restrict__ row_min, float* __restrict__ rms)
{
    int i = blockIdx.x * 256 + threadIdx.x;
    if (i < BATCH * NPAD) {
        int j = i & (NPAD - 1);
        float rm = row_min[i];
        rms[i] = (j < NPAT) ? (1.0f / (float)DDIM) / (rm + ALPHA)
                            : __builtin_inff();
    }
}

// -------------------- panel-persistent fused GEMM passes --------------------
// 512 threads (8 waves = 2/SIMD). Panel operand fragments live in REGISTERS
// (p_reg[5][4], loaded once); stream operand double-buffered in LDS.
// Wave layout: wp=wid>>2 (2 panel groups x 64 rows), ws=wid&3 (4 stream
// groups x 32 cols). Per tile per wave: 10 ds_read_b128 + 40 MFMA.
// PASS 1: panel=Y rows; row-min in regs -> ONE plain store per row.
// PASS 2: panel=X cols; col-min in regs -> one atomicAdd partial per block.
template <int PASS>
__global__ __launch_bounds__(512, 2) void panel_pass(
    const __hip_bfloat16* __restrict__ Xp,   // [B][NPAD][KPAD]
    const __hip_bfloat16* __restrict__ Yp,   // [B][NPAD][KPAD]
    const float* __restrict__ x2,
    const float* __restrict__ y2,
    const float* __restrict__ rms,           // PASS2 only
    float* __restrict__ row_min,
    float* __restrict__ out)                 // PASS2 only
{
    __shared__ __align__(16) __hip_bfloat16 S[2][NCHK * TILE * 32]; // 2 x 40 KB
    __shared__ float sm_a[2][TILE];   // stream smalls: x2 (P1) / y2 (P2)
    __shared__ float sm_b[2][TILE];   // P2: rms
    __shared__ float pnl[TILE];       // panel small: y2 (P1) / x2 (P2)
    __shared__ float red[4][TILE];    // cross-wave reduce

    int blk = blockIdx.x;
    int bz  = blk & 3;               // image (2 XCDs per image under %8 rr)
    int tP  = blk >> 2;              // panel index 0..63
    int tid = threadIdx.x;
    int wid = tid >> 6, lane = tid & 63;
    int wp  = wid >> 2;              // panel group (2)
    int ws  = wid & 3;               // stream group (4)

    const __hip_bfloat16* Pbase =
        (PASS == 1 ? Yp : Xp) + ((size_t)bz * NPAD + tP * TILE) * KPAD;
    const __hip_bfloat16* Sbase =
        (PASS == 1 ? Xp : Yp) + (size_t)bz * NPAD * KPAD;
    const float* pnl_src = (PASS == 1 ? y2 : x2) + (size_t)bz * NPAD + tP * TILE;
    const float* sma_src = (PASS == 1 ? x2 : y2) + (size_t)bz * NPAD;
    const float* smb_src = rms + (size_t)bz * NPAD;

    // stage one 128x160 bf16 tile: 5 async16/thread (one per chunk)
    auto stageS = [&](int buf, const __hip_bfloat16* gsrc) {
        int row  = wid * 16 + (lane >> 2);
        int slog = (lane & 3) ^ ((row >> 1) & 3);       // inverse swz on src
        const __hip_bfloat16* src = gsrc + (size_t)row * KPAD + slog * 8;
        __hip_bfloat16* dbase = &S[buf][wid * 512];     // wave-uniform dest
        for (int c = 0; c < NCHK; ++c)
            async16(src + c * 32, dbase + c * 4096);
    };
    auto stage_small = [&](int buf, int t) {
        if (wid == 0 && lane < 32)
            async16(sma_src + (size_t)t * TILE + lane * 4, &sm_a[buf][0]);
        if (PASS == 2 && wid == 4 && lane < 32)
            async16(smb_src + (size_t)t * TILE + lane * 4, &sm_b[buf][0]);
    };

    // prologue: panel -> S1; tile0 -> S0; smalls; panel scalars
    stageS(1, Pbase);
    stageS(0, Sbase);
    stage_small(0, 0);
    if (wid == 2 && lane < 32) async16(pnl_src + lane * 4, &pnl[0]);
    __syncthreads();                 // vmcnt(0): everything landed

    int fr    = lane & 15;
    int sread = ((lane >> 4) ^ ((lane >> 1) & 3)) * 8;  // swz read slot
    int prow  = wp * 64 + fr;

    // panel fragments -> registers (20 ds_read_b128, once)
    short8 p_reg[NCHK][4];
#pragma unroll
    for (int c = 0; c < NCHK; ++c)
#pragma unroll
        for (int m = 0; m < 4; ++m)
            p_reg[c][m] =
                *(const short8*)&S[1][c * 4096 + (prow + m * 16) * 32 + sread];

    float xv[4];   // PASS2: own panel cols' x2 (fixed per lane)
    if (PASS == 2)
#pragma unroll
        for (int nb = 0; nb < 4; ++nb) xv[nb] = pnl[wp * 64 + nb * 16 + fr];

    __syncthreads();                 // all waves done reading S1 -> reusable

    float runmin[PASS == 1 ? 16 : 4];
#pragma unroll
    for (int i = 0; i < (PASS == 1 ? 16 : 4); ++i)
        runmin[i] = __builtin_inff();

    int srow = ws * 32 + fr;         // stream fragment row base

#pragma unroll 1
    for (int t = 0; t < NT; ++t) {
        int cur = t & 1;
        if (t + 1 < NT) {            // prefetch next tile (overlaps compute)
            stageS(cur ^ 1, Sbase + (size_t)(t + 1) * TILE * KPAD);
            stage_small(cur ^ 1, t + 1);
        }

        if (PASS == 1) {
            f32x4 acc[4][2] = {};
#pragma unroll
            for (int c = 0; c < NCHK; ++c) {
                short8 s0 = *(const short8*)&S[cur][c * 4096 + srow * 32 + sread];
                short8 s1 = *(const short8*)&S[cur][c * 4096 + (srow + 16) * 32 + sread];
#pragma unroll
                for (int m = 0; m < 4; ++m) {
                    acc[m][0] = __builtin_amdgcn_mfma_f32_16x16x32_bf16(
                        p_reg[c][m], s0, acc[m][0], 0, 0, 0);
                    acc[m][1] = __builtin_amdgcn_mfma_f32_16x16x32_bf16(
                        p_reg[c][m], s1, acc[m][1], 0, 0, 0);
                }
            }
            int gcb = t * TILE;
            float xvn[2];
#pragma unroll
            for (int n = 0; n < 2; ++n) {
                int ic = ws * 32 + n * 16 + fr;
                xvn[n] = (gcb + ic < NPAT) ? sm_a[cur][ic] : __builtin_inff();
            }
#pragma unroll
            for (int m = 0; m < 4; ++m)
#pragma unroll
                for (int reg = 0; reg < 4; ++reg)
#pragma unroll
                    for (int n = 0; n < 2; ++n)
                        runmin[m * 4 + reg] = fminf(runmin[m * 4 + reg],
                            fmaf(-2.0f, acc[m][n][reg], xvn[n]));
        } else {
            f32x4 acc[2][4] = {};
#pragma unroll
            for (int c = 0; c < NCHK; ++c) {
                short8 s0 = *(const short8*)&S[cur][c * 4096 + srow * 32 + sread];
                short8 s1 = *(const short8*)&S[cur][c * 4096 + (srow + 16) * 32 + sread];
#pragma unroll
                for (int nb = 0; nb < 4; ++nb) {
                    acc[0][nb] = __builtin_amdgcn_mfma_f32_16x16x32_bf16(
                        s0, p_reg[c][nb], acc[0][nb], 0, 0, 0);
                    acc[1][nb] = __builtin_amdgcn_mfma_f32_16x16x32_bf16(
                        s1, p_reg[c][nb], acc[1][nb], 0, 0, 0);
                }
            }
#pragma unroll
            for (int ma = 0; ma < 2; ++ma)
#pragma unroll
                for (int reg = 0; reg < 4; ++reg) {
                    int jl = ws * 32 + ma * 16 + (lane >> 4) * 4 + reg;
                    float yv = sm_a[cur][jl];
                    float rr = sm_b[cur][jl];   // +inf on pad rows (prep_rms)
#pragma unroll
                    for (int nb = 0; nb < 4; ++nb)
                        runmin[nb] = fminf(runmin[nb],
                            fmaf(-2.0f, acc[ma][nb][reg], yv + xv[nb]) * rr);
                }
        }
        __syncthreads();             // drains prefetch + buffer handshake
    }

    if (PASS == 1) {
        // lane-group reduce over stream cols -> cross-ws LDS -> plain store
#pragma unroll
        for (int m = 0; m < 4; ++m)
#pragma unroll
            for (int reg = 0; reg < 4; ++reg) {
                float v = runmin[m * 4 + reg];
                for (int s = 1; s < 16; s <<= 1)
                    v = fminf(v, __shfl_xor(v, s));
                if ((lane & 15) == 0)
                    red[ws][wp * 64 + m * 16 + (lane >> 4) * 4 + reg] = v;
            }
        __syncthreads();
        if (tid < TILE) {
            float mv = fminf(fminf(red[0][tid], red[1][tid]),
                             fminf(red[2][tid], red[3][tid]));
            float rm = fmaxf(pnl[tid] + mv, 0.f) * (1.0f / (float)DDIM);
            row_min[(size_t)bz * NPAD + tP * TILE + tid] = rm;
        }
    } else {
        // reduce over stream rows -> cross-ws LDS -> clamp/mask -> 1 atomic
#pragma unroll
        for (int nb = 0; nb < 4; ++nb) {
            float v = runmin[nb];
            v = fminf(v, __shfl_xor(v, 16));
            v = fminf(v, __shfl_xor(v, 32));
            if (lane < 16) red[ws][wp * 64 + nb * 16 + lane] = v;
        }
        __syncthreads();
        if (tid < TILE) {
            int gc = tP * TILE + tid;
            float cv = fminf(fminf(red[0][tid], red[1][tid]),
                             fminf(red[2][tid], red[3][tid]));
            cv = fmaxf(cv, 0.f);                   // deferred clamp (monotone)
            red[0][tid] = (gc < NPAT) ? cv : 0.f;  // mask pad cols
        }
        __syncthreads();
        if (tid < 64) {
            float s = red[0][tid] + red[0][tid + 64];
            for (int o = 32; o; o >>= 1) s += __shfl_down(s, o);
            if (tid == 0)
                atomicAdd(out, s * (1.0f / (float)(BATCH * NPAT)));
        }
    }
}

extern "C" void kernel_launch(void* const* d_in, const int* in_sizes, int n_in,
                              void* d_out, int out_size, void* d_ws, size_t ws_size,
                              hipStream_t stream) {
    const float* x = (const float*)d_in[0];
    const float* y = (const float*)d_in[1];
    float* out = (float*)d_out;

    char* ws = (char*)d_ws;
    size_t patSz = (size_t)BATCH * NPAD * KPAD * sizeof(__hip_bfloat16); // 10.5 MB
    __hip_bfloat16* Xp = (__hip_bfloat16*)ws;
    __hip_bfloat16* Yp = (__hip_bfloat16*)(ws + patSz);
    float* x2 = (float*)(ws + 2 * patSz);
    float* y2 = x2 + BATCH * NPAD;
    float* row_min = y2 + BATCH * NPAD;
    float* rms = row_min + BATCH * NPAD;

    dim3 eg(NPAD / 4, BATCH);
    extract_patches<<<eg, 256, 0, stream>>>(x, Xp, x2, out);   // zeroes out
    extract_patches<<<eg, 256, 0, stream>>>(y, Yp, y2, nullptr);

    panel_pass<1><<<NT * BATCH, 512, 0, stream>>>(Xp, Yp, x2, y2, rms,
                                                  row_min, out);
    prep_rms<<<(BATCH * NPAD) / 256, 256, 0, stream>>>(row_min, rms);
    panel_pass<2><<<NT * BATCH, 512, 0, stream>>>(Xp, Yp, x2, y2, rms,
                                                  row_min, out);
}